// Round 2
// baseline (133.557 us; speedup 1.0000x reference)
//
#include <hip/hip_runtime.h>

// ---------------------------------------------------------------------------
// TaskAlignedAssigner (YOLO TAL) for MI355X.
// B=32, A=8400, M=32, C=80 (derived at runtime from in_sizes; M<=32 assumed
// so a gt-column mask fits one uint32 per anchor).
//
// Outputs (concatenated float32, return order):
//   tl  (B,A)    off 0
//   tb  (B,A,4)  off BA
//   ts  (B,A,C)  off BA*5
//   fg  (B,A)    off BA*(5+C)
//   tgt (B,A)    off BA*(6+C)
//
// R1: removed global atomic histogram from k_select1 (65us of same-cacheline
// atomic serialization); k_fix2 now builds the per-gt histogram itself via
// per-wave ballot counting into LDS.
// ---------------------------------------------------------------------------

#define EPS_IN   1e-9f
#define IOU_EPS  1e-7f

// IoU exactly as reference (_iou_xyxy) with clip(.,0); fp contraction off so
// results are bit-identical across kernels and match plain IEEE numpy eval.
__device__ __forceinline__ float iou_pair(const float4 p, const float4 g) {
#pragma clang fp contract(off)
    float w1 = p.z - p.x;
    float h1 = (p.w - p.y) + IOU_EPS;
    float w2 = g.z - g.x;
    float h2 = (g.w - g.y) + IOU_EPS;
    float iw = fminf(p.z, g.z) - fmaxf(p.x, g.x);
    iw = fmaxf(iw, 0.0f);
    float ih = fminf(p.w, g.w) - fmaxf(p.y, g.y);
    ih = fmaxf(ih, 0.0f);
    float inter = iw * ih;
    float uni = w1 * h1 + w2 * h2 - inter + IOU_EPS;
    float r = inter / uni;
    return fmaxf(r, 0.0f);
}

// mask_gt is bool in JAX; harness storage dtype unknown -> runtime-detected.
// mode 0: int32, mode 1: float32, mode 2: uint8
__device__ __forceinline__ bool mask_at(const void* mg, int mode, int idx) {
    if (mode == 0) return ((const int*)mg)[idx] != 0;
    if (mode == 1) return ((const float*)mg)[idx] != 0.0f;
    return ((const unsigned char*)mg)[idx] != 0;
}

// K0: detect mask_gt storage mode.
__global__ void k_init(const void* mg, int nwords, int* mode) {
    __shared__ int okI, okF;
    if (threadIdx.x == 0) { okI = 1; okF = 1; }
    __syncthreads();
    const unsigned* w = (const unsigned*)mg;
    int badI = 0, badF = 0;
    for (int i = threadIdx.x; i < nwords; i += blockDim.x) {
        unsigned v = w[i];
        if (v > 1u) badI = 1;
        if (v != 0u && v != 0x3F800000u) badF = 1;
    }
    if (badI) atomicAnd(&okI, 0);
    if (badF) atomicAnd(&okF, 0);
    __syncthreads();
    if (threadIdx.x == 0) mode[0] = okI ? 0 : (okF ? 1 : 2);
}

// K1: rowbits[b][a] = bitmask over m of (anchor strictly inside gt m && mask_gt[m])
__global__ void k_inmask(const float* __restrict__ anc, const float* __restrict__ gtb,
                         const void* mg, const int* modep,
                         unsigned* __restrict__ rowbits, int A, int M) {
    int b = blockIdx.y;
    int a = blockIdx.x * blockDim.x + threadIdx.x;
    __shared__ float4 sg[32];
    __shared__ unsigned char smg[32];
    int mode = modep[0];
    if (threadIdx.x < M) {
        sg[threadIdx.x]  = ((const float4*)gtb)[b * M + threadIdx.x];
        smg[threadIdx.x] = mask_at(mg, mode, b * M + threadIdx.x) ? 1 : 0;
    }
    __syncthreads();
    if (a >= A) return;
    float2 an = ((const float2*)anc)[a];
    unsigned bits = 0u;
    for (int m = 0; m < M; m++) {
        float4 g = sg[m];
        float mn = fminf(fminf(an.x - g.x, an.y - g.y), fminf(g.z - an.x, g.w - an.y));
        if (mn > EPS_IN && smg[m]) bits |= (1u << m);
    }
    rowbits[(size_t)b * A + a] = bits;
}

// K2: per (b,m) column: argmax_a overlaps (key with first-index tiebreak) +
// hasIn; store colKey; fused fix-1: if mask_gt[m] && !hasIn, OR bit m into
// the best anchor's row (only reads geometry, never rowbits -> race-free).
__global__ void k_colreduce(const float* __restrict__ pdb, const float* __restrict__ anc,
                            const float* __restrict__ gtb, const void* mg, const int* modep,
                            unsigned* __restrict__ rowbits,
                            unsigned long long* __restrict__ colKey, int A, int M) {
    int b = blockIdx.y, m = blockIdx.x;
    float4 g = ((const float4*)gtb)[b * M + m];
    unsigned long long key = 0ull;   // below any real key (low word >= ~(A-1) > 0)
    int hasin = 0;
    for (int a = threadIdx.x; a < A; a += blockDim.x) {
        float4 p = ((const float4*)pdb)[(size_t)b * A + a];
        float v = iou_pair(p, g);
        unsigned long long k =
            ((unsigned long long)__float_as_uint(v) << 32) | (0xFFFFFFFFu - (unsigned)a);
        if (k > key) key = k;
        float2 an = ((const float2*)anc)[a];
        float mn = fminf(fminf(an.x - g.x, an.y - g.y), fminf(g.z - an.x, g.w - an.y));
        if (mn > EPS_IN) hasin = 1;
    }
    __shared__ unsigned long long skey[4];
    __shared__ int sin[4];
    int lane = threadIdx.x & 63, wid = threadIdx.x >> 6;
    for (int off = 32; off > 0; off >>= 1) {
        unsigned long long o = __shfl_down(key, off);
        if (o > key) key = o;
        hasin |= __shfl_down(hasin, off);
    }
    if (lane == 0) { skey[wid] = key; sin[wid] = hasin; }
    __syncthreads();
    if (threadIdx.x == 0) {
        int nw = (int)(blockDim.x >> 6);
        for (int i = 1; i < nw; i++) { if (skey[i] > key) key = skey[i]; hasin |= sin[i]; }
        colKey[b * M + m] = key;
        int mode = modep[0];
        if (!hasin && mask_at(mg, mode, b * M + m)) {
            unsigned besta = 0xFFFFFFFFu - (unsigned)(key & 0xFFFFFFFFull);
            atomicOr(&rowbits[(size_t)b * A + besta], 1u << m);
        }
    }
}

// K3: _select_highest_overlaps #1 (dedup multi-gt anchors by full-row overlap
// argmax) + compact tgt (-1 = background). No global atomics (R1 fix).
__global__ void k_select1(const float* __restrict__ pdb, const float* __restrict__ gtb,
                          unsigned* __restrict__ rowbits, int* __restrict__ tgtfg,
                          int A, int M) {
    int b = blockIdx.y;
    int a = blockIdx.x * blockDim.x + threadIdx.x;
    __shared__ float4 sg[32];
    if (threadIdx.x < M) sg[threadIdx.x] = ((const float4*)gtb)[b * M + threadIdx.x];
    __syncthreads();
    if (a >= A) return;
    size_t idx = (size_t)b * A + a;
    unsigned bits = rowbits[idx];
    int pc = __popc(bits);
    int tgt;
    if (pc > 1) {
        float4 p = ((const float4*)pdb)[idx];
        float bv = -1.0f; int bm = 0;
        for (int m = 0; m < M; m++) {
            float v = iou_pair(p, sg[m]);
            if (v > bv) { bv = v; bm = m; }
        }
        rowbits[idx] = 1u << bm;
        tgt = bm;
    } else if (pc == 1) {
        tgt = __ffs(bits) - 1;
    } else { tgt = -1; }
    tgtfg[idx] = tgt;
}

// K4: fix-2 sequential per-gt reassignment scan (order-dependent). One block
// per batch: phase 1 builds the per-gt assignment histogram from tgtfg via
// per-wave ballot counting (no global atomics); phase 2 thread 0 runs the
// serial scan.
__global__ void k_fix2(const void* mg, const int* modep,
                       const unsigned long long* __restrict__ colKey,
                       int* __restrict__ tgtfg,
                       unsigned* __restrict__ rowbits, int A, int M) {
    int b = blockIdx.x;
    int tid = threadIdx.x;
    int lane = tid & 63;
    __shared__ int cl[32];
    if (tid < 32) cl[tid] = 0;
    __syncthreads();
    int span = ((A + blockDim.x - 1) / blockDim.x) * blockDim.x;
    for (int base = tid; base < span; base += blockDim.x) {
        int t = (base < A) ? tgtfg[(size_t)b * A + base] : -1;
        for (int m = 0; m < M; m++) {
            unsigned long long mk = __ballot(t == m);
            if (lane == 0 && mk) atomicAdd(&cl[m], __popcll(mk));
        }
    }
    __syncthreads();
    if (tid != 0) return;
    int mode = modep[0];
    for (int g = 0; g < M; g++) {
        if (!mask_at(mg, mode, b * M + g)) continue;
        if (cl[g] > 0) continue;
        unsigned long long key = colKey[b * M + g];
        int best = (int)(0xFFFFFFFFu - (unsigned)(key & 0xFFFFFFFFull));
        size_t idx = (size_t)b * A + best;
        int old = tgtfg[idx];
        if (old >= 0) cl[old]--;
        tgtfg[idx] = g;
        cl[g]++;
        rowbits[idx] |= (1u << g);
    }
}

// K5: _select_highest_overlaps #2 + all scalar outputs + norm (single
// pd_scores gather per anchor).
__global__ void k_final(const float* __restrict__ pds, const float* __restrict__ pdb,
                        const float* __restrict__ gtb, const int* __restrict__ gtl,
                        const unsigned* __restrict__ rowbits, float* __restrict__ out,
                        float* __restrict__ normArr, int* __restrict__ tlArr,
                        int A, int M, int C, int B) {
    int b = blockIdx.y;
    int a = blockIdx.x * blockDim.x + threadIdx.x;
    __shared__ float4 sg[32];
    __shared__ int sl[32];
    if (threadIdx.x < M) {
        sg[threadIdx.x] = ((const float4*)gtb)[b * M + threadIdx.x];
        sl[threadIdx.x] = gtl[b * M + threadIdx.x];
    }
    __syncthreads();
    if (a >= A) return;
    size_t idx = (size_t)b * A + a;
    unsigned bits = rowbits[idx];
    int pc = __popc(bits);
    int tgt, fg; float ov = 0.0f;
    float4 p = ((const float4*)pdb)[idx];
    if (pc > 1) {
        float bv = -1.0f; int bm = 0;
        for (int m = 0; m < M; m++) {
            float v = iou_pair(p, sg[m]);
            if (v > bv) { bv = v; bm = m; }
        }
        tgt = bm; fg = 1; ov = bv;
    } else if (pc == 1) {
        tgt = __ffs(bits) - 1; fg = 1;
        ov = iou_pair(p, sg[tgt]);
    } else { tgt = 0; fg = 0; }

    int lab = sl[tgt];
    int tl = min(max(lab, 0), C);        // clip(., 0, NUM_CLASSES)
    float norm = 0.0f;
    if (fg) {
        int li = (lab >= 0 && lab < C) ? lab : 0;
        float cls = pds[idx * (size_t)C + li];   // take_along_axis gather
        float ov6 = powf(ov, 6.0f);              // overlaps ** BETA
        float v = cls * ov6;                     // align_metric at (a, tgt)
        norm = v * ov / (v + 1e-9f);             // pam*pov/(pam+eps)
    }
    size_t BA = (size_t)B * A;
    out[idx] = (float)tl;                                // tl
    ((float4*)(out + BA))[idx] = sg[tgt];                // tb
    out[BA * (size_t)(5 + C) + idx] = fg ? 1.0f : 0.0f;  // fg
    out[BA * (size_t)(6 + C) + idx] = (float)tgt;        // tgt
    normArr[idx] = norm;
    tlArr[idx] = tl;
}

// K6: ts = one_hot(tl, C) * norm (norm already 0 where !fg). Coalesced float4.
__global__ void k_ts(const float* __restrict__ normArr, const int* __restrict__ tlArr,
                     float* __restrict__ ts, unsigned total_f4, int rowf4) {
    unsigned t = blockIdx.x * blockDim.x + threadIdx.x;
    if (t >= total_f4) return;
    unsigned row = t / (unsigned)rowf4;
    int c4 = (int)(t - row * (unsigned)rowf4);
    float nv = normArr[row];
    int tl = tlArr[row];
    int base = c4 * 4;
    float4 v;
    v.x = (tl == base + 0) ? nv : 0.0f;
    v.y = (tl == base + 1) ? nv : 0.0f;
    v.z = (tl == base + 2) ? nv : 0.0f;
    v.w = (tl == base + 3) ? nv : 0.0f;
    ((float4*)ts)[t] = v;
}

extern "C" void kernel_launch(void* const* d_in, const int* in_sizes, int n_in,
                              void* d_out, int out_size, void* d_ws, size_t ws_size,
                              hipStream_t stream) {
    const float* pd_scores = (const float*)d_in[0];
    const float* pd_bboxes = (const float*)d_in[1];
    const float* anc       = (const float*)d_in[2];
    const int*   gt_labels = (const int*)d_in[3];
    const float* gt_bboxes = (const float*)d_in[4];
    const void*  mask_gt   = d_in[5];

    int A  = in_sizes[2] / 2;
    int B  = in_sizes[1] / (A * 4);
    int M  = in_sizes[3] / B;
    int C  = (int)((long long)in_sizes[0] / ((long long)B * A));

    // workspace carve (256B aligned chunks)
    char* wp = (char*)d_ws;
    auto carve = [&](size_t bytes) -> char* {
        char* r = wp; wp += (bytes + 255) & ~(size_t)255; return r;
    };
    int* mode                    = (int*)carve(16);
    unsigned* rowbits            = (unsigned*)carve((size_t)B * A * 4);
    int* tgtfg                   = (int*)carve((size_t)B * A * 4);
    unsigned long long* colKey   = (unsigned long long*)carve((size_t)B * M * 8);
    float* normArr               = (float*)carve((size_t)B * A * 4);
    int* tlArr                   = (int*)carve((size_t)B * A * 4);

    float* out = (float*)d_out;

    int nCh = (A + 255) / 256;
    dim3 gAB(nCh, B);
    dim3 gMB(M, B);

    k_init<<<1, 256, 0, stream>>>(mask_gt, (B * M) / 4, mode);
    k_inmask<<<gAB, 256, 0, stream>>>(anc, gt_bboxes, mask_gt, mode, rowbits, A, M);
    k_colreduce<<<gMB, 256, 0, stream>>>(pd_bboxes, anc, gt_bboxes, mask_gt, mode,
                                         rowbits, colKey, A, M);
    k_select1<<<gAB, 256, 0, stream>>>(pd_bboxes, gt_bboxes, rowbits, tgtfg, A, M);
    k_fix2<<<B, 256, 0, stream>>>(mask_gt, mode, colKey, tgtfg, rowbits, A, M);
    k_final<<<gAB, 256, 0, stream>>>(pd_scores, pd_bboxes, gt_bboxes, gt_labels,
                                     rowbits, out, normArr, tlArr, A, M, C, B);
    unsigned total_f4 = (unsigned)((size_t)B * A * (C / 4));
    unsigned nB = (total_f4 + 255u) / 256u;
    k_ts<<<nB, 256, 0, stream>>>(normArr, tlArr, out + (size_t)B * A * 5, total_f4, C / 4);
}

// Round 3
// 71.452 us; speedup vs baseline: 1.8692x; 1.8692x over previous
//
#include <hip/hip_runtime.h>

// ---------------------------------------------------------------------------
// TaskAlignedAssigner (YOLO TAL) for MI355X.
// B=32, A=8400, M=32, C=80 (derived at runtime from in_sizes; M<=32 assumed
// so a gt-column mask fits one uint32 per anchor).
//
// Outputs (concatenated float32, return order):
//   tl  (B,A)    off 0
//   tb  (B,A,4)  off BA
//   ts  (B,A,C)  off BA*5
//   fg  (B,A)    off BA*(5+C)
//   tgt (B,A)    off BA*(6+C)
//
// R1: removed global atomic histogram from k_select1 (65us same-cacheline
//     atomic serialization).
// R2: k_fix2 rewritten — LDS-atomic histogram (no ballot chains), parallel
//     prefetch of all serial-scan inputs, and the order-dependent 32-step
//     scan runs wave-parallel in registers (shfl only; global side effects
//     are fire-and-forget stores/atomicOr). R1's version was 71.7us of
//     dependent global-latency chains at 1% occupancy.
// ---------------------------------------------------------------------------

#define EPS_IN   1e-9f
#define IOU_EPS  1e-7f

// IoU exactly as reference (_iou_xyxy) with clip(.,0); fp contraction off so
// results are bit-identical across kernels and match plain IEEE numpy eval.
__device__ __forceinline__ float iou_pair(const float4 p, const float4 g) {
#pragma clang fp contract(off)
    float w1 = p.z - p.x;
    float h1 = (p.w - p.y) + IOU_EPS;
    float w2 = g.z - g.x;
    float h2 = (g.w - g.y) + IOU_EPS;
    float iw = fminf(p.z, g.z) - fmaxf(p.x, g.x);
    iw = fmaxf(iw, 0.0f);
    float ih = fminf(p.w, g.w) - fmaxf(p.y, g.y);
    ih = fmaxf(ih, 0.0f);
    float inter = iw * ih;
    float uni = w1 * h1 + w2 * h2 - inter + IOU_EPS;
    float r = inter / uni;
    return fmaxf(r, 0.0f);
}

// mask_gt is bool in JAX; harness storage dtype unknown -> runtime-detected.
// mode 0: int32, mode 1: float32, mode 2: uint8
__device__ __forceinline__ bool mask_at(const void* mg, int mode, int idx) {
    if (mode == 0) return ((const int*)mg)[idx] != 0;
    if (mode == 1) return ((const float*)mg)[idx] != 0.0f;
    return ((const unsigned char*)mg)[idx] != 0;
}

// K0: detect mask_gt storage mode.
__global__ void k_init(const void* mg, int nwords, int* mode) {
    __shared__ int okI, okF;
    if (threadIdx.x == 0) { okI = 1; okF = 1; }
    __syncthreads();
    const unsigned* w = (const unsigned*)mg;
    int badI = 0, badF = 0;
    for (int i = threadIdx.x; i < nwords; i += blockDim.x) {
        unsigned v = w[i];
        if (v > 1u) badI = 1;
        if (v != 0u && v != 0x3F800000u) badF = 1;
    }
    if (badI) atomicAnd(&okI, 0);
    if (badF) atomicAnd(&okF, 0);
    __syncthreads();
    if (threadIdx.x == 0) mode[0] = okI ? 0 : (okF ? 1 : 2);
}

// K1: rowbits[b][a] = bitmask over m of (anchor strictly inside gt m && mask_gt[m])
__global__ void k_inmask(const float* __restrict__ anc, const float* __restrict__ gtb,
                         const void* mg, const int* modep,
                         unsigned* __restrict__ rowbits, int A, int M) {
    int b = blockIdx.y;
    int a = blockIdx.x * blockDim.x + threadIdx.x;
    __shared__ float4 sg[32];
    __shared__ unsigned char smg[32];
    int mode = modep[0];
    if (threadIdx.x < M) {
        sg[threadIdx.x]  = ((const float4*)gtb)[b * M + threadIdx.x];
        smg[threadIdx.x] = mask_at(mg, mode, b * M + threadIdx.x) ? 1 : 0;
    }
    __syncthreads();
    if (a >= A) return;
    float2 an = ((const float2*)anc)[a];
    unsigned bits = 0u;
    for (int m = 0; m < M; m++) {
        float4 g = sg[m];
        float mn = fminf(fminf(an.x - g.x, an.y - g.y), fminf(g.z - an.x, g.w - an.y));
        if (mn > EPS_IN && smg[m]) bits |= (1u << m);
    }
    rowbits[(size_t)b * A + a] = bits;
}

// K2: per (b,m) column: argmax_a overlaps (key with first-index tiebreak) +
// hasIn; store colKey; fused fix-1: if mask_gt[m] && !hasIn, OR bit m into
// the best anchor's row (only reads geometry, never rowbits -> race-free).
__global__ void k_colreduce(const float* __restrict__ pdb, const float* __restrict__ anc,
                            const float* __restrict__ gtb, const void* mg, const int* modep,
                            unsigned* __restrict__ rowbits,
                            unsigned long long* __restrict__ colKey, int A, int M) {
    int b = blockIdx.y, m = blockIdx.x;
    float4 g = ((const float4*)gtb)[b * M + m];
    unsigned long long key = 0ull;   // below any real key (low word >= ~(A-1) > 0)
    int hasin = 0;
    for (int a = threadIdx.x; a < A; a += blockDim.x) {
        float4 p = ((const float4*)pdb)[(size_t)b * A + a];
        float v = iou_pair(p, g);
        unsigned long long k =
            ((unsigned long long)__float_as_uint(v) << 32) | (0xFFFFFFFFu - (unsigned)a);
        if (k > key) key = k;
        float2 an = ((const float2*)anc)[a];
        float mn = fminf(fminf(an.x - g.x, an.y - g.y), fminf(g.z - an.x, g.w - an.y));
        if (mn > EPS_IN) hasin = 1;
    }
    __shared__ unsigned long long skey[4];
    __shared__ int sin[4];
    int lane = threadIdx.x & 63, wid = threadIdx.x >> 6;
    for (int off = 32; off > 0; off >>= 1) {
        unsigned long long o = __shfl_down(key, off);
        if (o > key) key = o;
        hasin |= __shfl_down(hasin, off);
    }
    if (lane == 0) { skey[wid] = key; sin[wid] = hasin; }
    __syncthreads();
    if (threadIdx.x == 0) {
        int nw = (int)(blockDim.x >> 6);
        for (int i = 1; i < nw; i++) { if (skey[i] > key) key = skey[i]; hasin |= sin[i]; }
        colKey[b * M + m] = key;
        int mode = modep[0];
        if (!hasin && mask_at(mg, mode, b * M + m)) {
            unsigned besta = 0xFFFFFFFFu - (unsigned)(key & 0xFFFFFFFFull);
            atomicOr(&rowbits[(size_t)b * A + besta], 1u << m);
        }
    }
}

// K3: _select_highest_overlaps #1 (dedup multi-gt anchors by full-row overlap
// argmax) + compact tgt (-1 = background).
__global__ void k_select1(const float* __restrict__ pdb, const float* __restrict__ gtb,
                          unsigned* __restrict__ rowbits, int* __restrict__ tgtfg,
                          int A, int M) {
    int b = blockIdx.y;
    int a = blockIdx.x * blockDim.x + threadIdx.x;
    __shared__ float4 sg[32];
    if (threadIdx.x < M) sg[threadIdx.x] = ((const float4*)gtb)[b * M + threadIdx.x];
    __syncthreads();
    if (a >= A) return;
    size_t idx = (size_t)b * A + a;
    unsigned bits = rowbits[idx];
    int pc = __popc(bits);
    int tgt;
    if (pc > 1) {
        float4 p = ((const float4*)pdb)[idx];
        float bv = -1.0f; int bm = 0;
        for (int m = 0; m < M; m++) {
            float v = iou_pair(p, sg[m]);
            if (v > bv) { bv = v; bm = m; }
        }
        rowbits[idx] = 1u << bm;
        tgt = bm;
    } else if (pc == 1) {
        tgt = __ffs(bits) - 1;
    } else { tgt = -1; }
    tgtfg[idx] = tgt;
}

// K4: fix-2 sequential per-gt reassignment scan (order-dependent). One block
// per batch. Phase 1: LDS-atomic histogram of tgtfg. Phase 2: parallel
// prefetch of best-anchor, its current tgt, and mask bits. Phase 3: the
// 32-step serial scan runs wave-parallel in registers (lane m holds cl[m];
// dependent ops are shfl-only). Global side effects are fire-and-forget.
__global__ void k_fix2(const void* mg, const int* modep,
                       const unsigned long long* __restrict__ colKey,
                       int* __restrict__ tgtfg,
                       unsigned* __restrict__ rowbits, int A, int M) {
    int b = blockIdx.x;
    int tid = threadIdx.x;
    __shared__ int cl[32];
    __shared__ int sbest[32];
    __shared__ int spre[32];
    __shared__ unsigned smaskbits;
    if (tid < 32) cl[tid] = 0;
    __syncthreads();

    // Phase 1: histogram (no write to tgtfg anywhere before the scan).
    for (int a = tid; a < A; a += blockDim.x) {
        int t = tgtfg[(size_t)b * A + a];
        if (t >= 0) atomicAdd(&cl[t], 1);
    }

    // Phase 2: prefetch scan inputs (first wave).
    if (tid < 64) {
        bool mv = false;
        if (tid < M) {
            unsigned long long key = colKey[b * M + tid];
            int best = (int)(0xFFFFFFFFu - (unsigned)(key & 0xFFFFFFFFull));
            sbest[tid] = best;
            spre[tid]  = tgtfg[(size_t)b * A + best];
            mv = mask_at(mg, modep[0], b * M + tid);
        }
        unsigned long long bal = __ballot(mv);
        if (tid == 0) smaskbits = (unsigned)bal;
    }
    __syncthreads();
    if (tid >= 64) return;

    // Phase 3: wave-parallel serial scan. Lane m (m<32) holds count of gt m.
    int lane = tid;
    int myCnt  = (lane < 32) ? cl[lane]    : 0;
    int myBest = (lane < 32) ? sbest[lane] : -1;
    int myPre  = (lane < 32) ? spre[lane]  : -1;
    // eq[g] = bitmask over g2 of (best[g2] == best[g])
    unsigned myEq = 0;
    for (int g2 = 0; g2 < M; g2++) {
        int bb = __shfl(myBest, g2);
        if (bb == myBest) myEq |= (1u << g2);
    }
    unsigned maskbits = smaskbits;
    unsigned applied = 0;
    for (int g = 0; g < M; g++) {
        int cg = __shfl(myCnt, g);
        if (((maskbits >> g) & 1u) && cg == 0) {
            int a       = __shfl(myBest, g);
            unsigned em = __shfl(myEq, g);
            unsigned x  = applied & em;
            int old;
            if (x) old = 31 - __clz(x);          // last earlier step that took this anchor
            else   old = __shfl(myPre, g);       // select1's owner (-1 = background)
            if (lane == old) myCnt--;
            if (lane == g)   myCnt++;
            applied |= (1u << g);
            if (lane == 0) {
                tgtfg[(size_t)b * A + a] = g;                       // plain store
                atomicOr(&rowbits[(size_t)b * A + a], 1u << g);     // no return -> no stall
            }
        }
    }
}

// K5: _select_highest_overlaps #2 + all scalar outputs + norm (single
// pd_scores gather per anchor).
__global__ void k_final(const float* __restrict__ pds, const float* __restrict__ pdb,
                        const float* __restrict__ gtb, const int* __restrict__ gtl,
                        const unsigned* __restrict__ rowbits, float* __restrict__ out,
                        float* __restrict__ normArr, int* __restrict__ tlArr,
                        int A, int M, int C, int B) {
    int b = blockIdx.y;
    int a = blockIdx.x * blockDim.x + threadIdx.x;
    __shared__ float4 sg[32];
    __shared__ int sl[32];
    if (threadIdx.x < M) {
        sg[threadIdx.x] = ((const float4*)gtb)[b * M + threadIdx.x];
        sl[threadIdx.x] = gtl[b * M + threadIdx.x];
    }
    __syncthreads();
    if (a >= A) return;
    size_t idx = (size_t)b * A + a;
    unsigned bits = rowbits[idx];
    int pc = __popc(bits);
    int tgt, fg; float ov = 0.0f;
    float4 p = ((const float4*)pdb)[idx];
    if (pc > 1) {
        float bv = -1.0f; int bm = 0;
        for (int m = 0; m < M; m++) {
            float v = iou_pair(p, sg[m]);
            if (v > bv) { bv = v; bm = m; }
        }
        tgt = bm; fg = 1; ov = bv;
    } else if (pc == 1) {
        tgt = __ffs(bits) - 1; fg = 1;
        ov = iou_pair(p, sg[tgt]);
    } else { tgt = 0; fg = 0; }

    int lab = sl[tgt];
    int tl = min(max(lab, 0), C);        // clip(., 0, NUM_CLASSES)
    float norm = 0.0f;
    if (fg) {
        int li = (lab >= 0 && lab < C) ? lab : 0;
        float cls = pds[idx * (size_t)C + li];   // take_along_axis gather
        float ov6 = powf(ov, 6.0f);              // overlaps ** BETA
        float v = cls * ov6;                     // align_metric at (a, tgt)
        norm = v * ov / (v + 1e-9f);             // pam*pov/(pam+eps)
    }
    size_t BA = (size_t)B * A;
    out[idx] = (float)tl;                                // tl
    ((float4*)(out + BA))[idx] = sg[tgt];                // tb
    out[BA * (size_t)(5 + C) + idx] = fg ? 1.0f : 0.0f;  // fg
    out[BA * (size_t)(6 + C) + idx] = (float)tgt;        // tgt
    normArr[idx] = norm;
    tlArr[idx] = tl;
}

// K6: ts = one_hot(tl, C) * norm (norm already 0 where !fg). Coalesced float4.
__global__ void k_ts(const float* __restrict__ normArr, const int* __restrict__ tlArr,
                     float* __restrict__ ts, unsigned total_f4, int rowf4) {
    unsigned t = blockIdx.x * blockDim.x + threadIdx.x;
    if (t >= total_f4) return;
    unsigned row = t / (unsigned)rowf4;
    int c4 = (int)(t - row * (unsigned)rowf4);
    float nv = normArr[row];
    int tl = tlArr[row];
    int base = c4 * 4;
    float4 v;
    v.x = (tl == base + 0) ? nv : 0.0f;
    v.y = (tl == base + 1) ? nv : 0.0f;
    v.z = (tl == base + 2) ? nv : 0.0f;
    v.w = (tl == base + 3) ? nv : 0.0f;
    ((float4*)ts)[t] = v;
}

extern "C" void kernel_launch(void* const* d_in, const int* in_sizes, int n_in,
                              void* d_out, int out_size, void* d_ws, size_t ws_size,
                              hipStream_t stream) {
    const float* pd_scores = (const float*)d_in[0];
    const float* pd_bboxes = (const float*)d_in[1];
    const float* anc       = (const float*)d_in[2];
    const int*   gt_labels = (const int*)d_in[3];
    const float* gt_bboxes = (const float*)d_in[4];
    const void*  mask_gt   = d_in[5];

    int A  = in_sizes[2] / 2;
    int B  = in_sizes[1] / (A * 4);
    int M  = in_sizes[3] / B;
    int C  = (int)((long long)in_sizes[0] / ((long long)B * A));

    // workspace carve (256B aligned chunks)
    char* wp = (char*)d_ws;
    auto carve = [&](size_t bytes) -> char* {
        char* r = wp; wp += (bytes + 255) & ~(size_t)255; return r;
    };
    int* mode                    = (int*)carve(16);
    unsigned* rowbits            = (unsigned*)carve((size_t)B * A * 4);
    int* tgtfg                   = (int*)carve((size_t)B * A * 4);
    unsigned long long* colKey   = (unsigned long long*)carve((size_t)B * M * 8);
    float* normArr               = (float*)carve((size_t)B * A * 4);
    int* tlArr                   = (int*)carve((size_t)B * A * 4);

    float* out = (float*)d_out;

    int nCh = (A + 255) / 256;
    dim3 gAB(nCh, B);
    dim3 gMB(M, B);

    k_init<<<1, 256, 0, stream>>>(mask_gt, (B * M) / 4, mode);
    k_inmask<<<gAB, 256, 0, stream>>>(anc, gt_bboxes, mask_gt, mode, rowbits, A, M);
    k_colreduce<<<gMB, 256, 0, stream>>>(pd_bboxes, anc, gt_bboxes, mask_gt, mode,
                                         rowbits, colKey, A, M);
    k_select1<<<gAB, 256, 0, stream>>>(pd_bboxes, gt_bboxes, rowbits, tgtfg, A, M);
    k_fix2<<<B, 1024, 0, stream>>>(mask_gt, mode, colKey, tgtfg, rowbits, A, M);
    k_final<<<gAB, 256, 0, stream>>>(pd_scores, pd_bboxes, gt_bboxes, gt_labels,
                                     rowbits, out, normArr, tlArr, A, M, C, B);
    unsigned total_f4 = (unsigned)((size_t)B * A * (C / 4));
    unsigned nB = (total_f4 + 255u) / 256u;
    k_ts<<<nB, 256, 0, stream>>>(normArr, tlArr, out + (size_t)B * A * 5, total_f4, C / 4);
}